// Round 4
// baseline (652.661 us; speedup 1.0000x reference)
//
#include <hip/hip_runtime.h>

typedef __bf16 bf16x8 __attribute__((ext_vector_type(8)));
typedef __bf16 bf16x4 __attribute__((ext_vector_type(4)));
typedef float  f32x4  __attribute__((ext_vector_type(4)));
typedef _Float16 f16x8 __attribute__((ext_vector_type(8)));
typedef _Float16 f16x4 __attribute__((ext_vector_type(4)));

#define MFMA16(A, B, C) __builtin_amdgcn_mfma_f32_16x16x32_bf16(A, B, C, 0, 0, 0)

#if __has_builtin(__builtin_amdgcn_exp2f)
#define EXP2F(x) __builtin_amdgcn_exp2f(x)
#else
#define EXP2F(x) exp2f(x)
#endif

// ---------------- elementwise fp32 -> bf16 ----------------
__global__ __launch_bounds__(256) void convert_f32_bf16(const float* __restrict__ src,
                                                        __bf16* __restrict__ dst) {
    size_t i = ((size_t)blockIdx.x * 256 + threadIdx.x) * 4;
    float4 v = *(const float4*)(src + i);
    bf16x4 o;
    o.x = (__bf16)v.x; o.y = (__bf16)v.y; o.z = (__bf16)v.z; o.w = (__bf16)v.w;
    *(bf16x4*)(dst + i) = o;
}

// ---------------- 2048x2048 fp32 -> bf16 transpose (W -> W^T rows=[n][k]) ----------------
__global__ __launch_bounds__(256) void transpose_conv(const float* __restrict__ src,
                                                      __bf16* __restrict__ dst) {
    __shared__ float t[32][33];
    int x0 = blockIdx.x * 32, y0 = blockIdx.y * 32;
    int tx = threadIdx.x, ty = threadIdx.y;   // 32x8
    for (int r = 0; r < 4; ++r)
        t[ty + 8 * r][tx] = src[(size_t)(y0 + ty + 8 * r) * 2048 + x0 + tx];
    __syncthreads();
    for (int r = 0; r < 4; ++r)
        dst[(size_t)(x0 + ty + 8 * r) * 2048 + y0 + tx] = (__bf16)t[tx][ty + 8 * r];
}

// ---------------- per-head V transpose: qkv[s][4096+h*128+d] -> vtb[h][d][s] ----------------
__global__ __launch_bounds__(256) void v_transpose(const __bf16* __restrict__ qkv,
                                                   __bf16* __restrict__ vtb) {
    __shared__ __bf16 t[32][33];
    int h = blockIdx.z;
    int s0 = blockIdx.x * 32, d0 = blockIdx.y * 32;
    int tx = threadIdx.x, ty = threadIdx.y;   // 32x8
    for (int r = 0; r < 4; ++r)
        t[ty + 8 * r][tx] = qkv[(size_t)(s0 + ty + 8 * r) * 6144 + 4096 + h * 128 + d0 + tx];
    __syncthreads();
    for (int r = 0; r < 4; ++r)
        vtb[(size_t)h * 128 * 4096 + (size_t)(d0 + ty + 8 * r) * 4096 + s0 + tx] = t[tx][ty + 8 * r];
}

// ---------------- fused RMSNorm + RoPE; head-major Q (pre-scaled by log2e/sqrt(128)) and K ----------------
__global__ __launch_bounds__(256) void rmsrope(const __bf16* __restrict__ qkv,
                                               const float* __restrict__ qw,
                                               const float* __restrict__ kw,
                                               const int* __restrict__ pos_ids,
                                               __bf16* __restrict__ qhb,
                                               __bf16* __restrict__ khb) {
    int u = blockIdx.x * 4 + (threadIdx.x >> 6);
    int s = u >> 5;
    int slot = u & 31;                  // 0-15 = q heads, 16-31 = k heads
    int lane = threadIdx.x & 63;        // handles dim pair (2*lane, 2*lane+1)
    bool isQ = slot < 16;
    int h = slot & 15;
    size_t base = (size_t)s * 6144 + (isQ ? 0 : 2048) + h * 128 + lane * 2;
    float x0 = (float)qkv[base], x1 = (float)qkv[base + 1];
    float ss = x0 * x0 + x1 * x1;
    for (int m = 1; m < 64; m <<= 1) ss += __shfl_xor(ss, m);
    float rr = rsqrtf(ss * (1.0f / 128.0f) + 1e-6f);
    const float* wp = isQ ? qw : kw;
    float n0 = x0 * rr * wp[lane * 2], n1 = x1 * rr * wp[lane * 2 + 1];
    float freq = EXP2F((float)lane * -0.2076205059304601f);
    float ang = (float)pos_ids[s] * freq;
    float sn, cs;
    __sincosf(ang, &sn, &cs);
    float o0 = n0 * cs - n1 * sn;
    float o1 = n0 * sn + n1 * cs;
    if (isQ) { o0 *= 0.12751744416196178f; o1 *= 0.12751744416196178f; }
    __bf16* dst = (isQ ? qhb : khb) + (size_t)h * 4096 * 128 + (size_t)s * 128 + lane * 2;
    dst[0] = (__bf16)o0; dst[1] = (__bf16)o1;
}

// ---------------- generic bf16 MFMA GEMM: C[M,N] = A[M,K] * Bt[N,K]^T ----------------
template <bool F32OUT>
__global__ __launch_bounds__(256) void gemm_bt(const __bf16* __restrict__ A, int lda,
                                               const __bf16* __restrict__ Bt, int ldb,
                                               void* __restrict__ Cout, int ldc, int K) {
    __shared__ __bf16 as[128][32];   // unpadded: required by global_load_lds contiguity
    __shared__ __bf16 bs[128][32];
    const int m0 = blockIdx.x * 128, n0 = blockIdx.y * 128;
    const int t = threadIdx.x;
    const int lane = t & 63, w = t >> 6;
    const int wm = (w >> 1) * 64, wn = (w & 1) * 64;
    const int ln = lane & 15, quad = lane >> 4;
    auto as3 = (__attribute__((address_space(3))) uint32_t*)as;
    auto bs3 = (__attribute__((address_space(3))) uint32_t*)bs;
    f32x4 acc[4][4] = {};
    for (int k0 = 0; k0 < K; k0 += 32) {
        for (int c = 0; c < 2; ++c) {
            int g = c * 256 + t;               // 512 chunks of 16B per tile
            int row = g >> 2, kc = g & 3;
            const __bf16* ga = &A[(size_t)(m0 + row) * lda + k0 + kc * 8];
            const __bf16* gb = &Bt[(size_t)(n0 + row) * ldb + k0 + kc * 8];
            __builtin_amdgcn_global_load_lds((const __attribute__((address_space(1))) uint32_t*)ga,
                                             as3 + c * 1024 + w * 256, 16, 0, 0);
            __builtin_amdgcn_global_load_lds((const __attribute__((address_space(1))) uint32_t*)gb,
                                             bs3 + c * 1024 + w * 256, 16, 0, 0);
        }
        __syncthreads();
        bf16x8 af[4], bfr[4];
        for (int i = 0; i < 4; ++i) af[i] = *(const bf16x8*)&as[wm + i * 16 + ln][quad * 8];
        for (int j = 0; j < 4; ++j) bfr[j] = *(const bf16x8*)&bs[wn + j * 16 + ln][quad * 8];
        for (int i = 0; i < 4; ++i)
            for (int j = 0; j < 4; ++j)
                acc[i][j] = MFMA16(af[i], bfr[j], acc[i][j]);
        __syncthreads();
    }
    for (int i = 0; i < 4; ++i)
        for (int j = 0; j < 4; ++j)
            for (int r = 0; r < 4; ++r) {
                int row = m0 + wm + i * 16 + quad * 4 + r;
                int col = n0 + wn + j * 16 + ln;
                if (F32OUT) ((float*)Cout)[(size_t)row * ldc + col] = acc[i][j][r];
                else        ((__bf16*)Cout)[(size_t)row * ldc + col] = (__bf16)acc[i][j][r];
            }
}

// ---------------- flash attention v3: S^T formulation, fixed-max softmax, BM=128, split-K x2 ----------------
// S^T = K·Q^T so the C-frag holds 4 consecutive KEYS per lane at fixed q-row:
// P store = 8 ds_write_b64, P reload (B-operand of O^T = V^T·P^T) = 4 ds_read_b128.
// Fixed-max: |s*log2e| <= sqrt(128)*log2e = 16.33 < 16.5 (RMS-normed q,k), so p=exp2(s-16.5)
// is exact softmax after the final divide; split-K partials are additive.
__global__ __launch_bounds__(256, 3) void flash_attn(const __bf16* __restrict__ Q,
                                                     const __bf16* __restrict__ Kb,
                                                     const __bf16* __restrict__ Vt,
                                                     _Float16* __restrict__ On,
                                                     float* __restrict__ Ln) {
    __shared__ __bf16 ks[64][136];    // keys x dim (stride 68 words = 4 mod 32: min-phase)
    __shared__ __bf16 vs[128][72];    // dim x keys (stride 36 words = 4 mod 32)
    __shared__ __bf16 ps[4][32][72];  // per-wave P^T-able store: [qrow][key], stride 36 words
    const int h = blockIdx.y;
    const int m0 = blockIdx.x * 128;
    const int split = blockIdx.z;
    const int t = threadIdx.x;
    const int lane = t & 63, w = t >> 6;
    const int ln = lane & 15, quad = lane >> 4;
    const __bf16* Qh = Q + (size_t)h * 4096 * 128;
    const __bf16* Kh = Kb + (size_t)h * 4096 * 128;
    const __bf16* Vh = Vt + (size_t)h * 128 * 4096;

    // stage Q in two 64-row passes; wave w owns q-rows [w*32, w*32+32)
    bf16x8 qf[2][4];   // B-operand frags of Q^T == A-layout reads of Q rows
    for (int pass = 0; pass < 2; ++pass) {
        for (int i = 0; i < 4; ++i) {
            int chunk = t + i * 256;
            int row = chunk >> 4, cc = chunk & 15;
            *(uint4*)&ks[row][cc * 8] =
                *(const uint4*)&Qh[(size_t)(m0 + pass * 64 + row) * 128 + cc * 8];
        }
        __syncthreads();
        if ((w >> 1) == pass)
            for (int nt = 0; nt < 2; ++nt)
                for (int kk = 0; kk < 4; ++kk)
                    qf[nt][kk] = *(const bf16x8*)&ks[(w & 1) * 32 + nt * 16 + ln][kk * 32 + quad * 8];
        __syncthreads();
    }

    f32x4 oacc[8][2] = {};   // O^T C-frags: [d-tile][qrow-tile]
    float rs[2] = {0.f, 0.f};

    for (int kb = split * 32; kb < split * 32 + 32; ++kb) {
        for (int i = 0; i < 4; ++i) {   // stage K (64x128) and V^T (128x64)
            int chunk = t + i * 256;
            int row = chunk >> 4, cc = chunk & 15;
            *(uint4*)&ks[row][cc * 8] =
                *(const uint4*)&Kh[(size_t)(kb * 64 + row) * 128 + cc * 8];
            int vrow = chunk >> 3, vc = chunk & 7;
            *(uint4*)&vs[vrow][vc * 8] =
                *(const uint4*)&Vh[(size_t)vrow * 4096 + kb * 64 + vc * 8];
        }
        __syncthreads();

        // S^T = K·Q^T - 16.5 (A = K-frag, B = Q-frag; bias via C-init)
        f32x4 sacc[4][2];
        const f32x4 mC = {-16.5f, -16.5f, -16.5f, -16.5f};
        for (int mt = 0; mt < 4; ++mt) { sacc[mt][0] = mC; sacc[mt][1] = mC; }
        for (int mt = 0; mt < 4; ++mt)
            for (int kk = 0; kk < 4; ++kk) {
                bf16x8 kf = *(const bf16x8*)&ks[mt * 16 + ln][kk * 32 + quad * 8];
                sacc[mt][0] = MFMA16(kf, qf[0][kk], sacc[mt][0]);
                sacc[mt][1] = MFMA16(kf, qf[1][kk], sacc[mt][1]);
            }

        // p = exp2(s~): 4 consecutive keys per lane -> one b64 LDS write per frag
        for (int mt = 0; mt < 4; ++mt)
            for (int nt = 0; nt < 2; ++nt) {
                float p0 = EXP2F(sacc[mt][nt][0]), p1 = EXP2F(sacc[mt][nt][1]);
                float p2 = EXP2F(sacc[mt][nt][2]), p3 = EXP2F(sacc[mt][nt][3]);
                rs[nt] += (p0 + p1) + (p2 + p3);
                bf16x4 pv = {(__bf16)p0, (__bf16)p1, (__bf16)p2, (__bf16)p3};
                *(bf16x4*)&ps[w][nt * 16 + ln][mt * 16 + quad * 4] = pv;
            }

        // O^T += V^T·P^T (A = V^T-frag from vs, B = P^T-frag: b128 from ps)
        bf16x8 pb[2][2];
        for (int ks2 = 0; ks2 < 2; ++ks2)
            for (int nt = 0; nt < 2; ++nt)
                pb[ks2][nt] = *(const bf16x8*)&ps[w][nt * 16 + ln][ks2 * 32 + quad * 8];
        for (int mt = 0; mt < 8; ++mt)
            for (int ks2 = 0; ks2 < 2; ++ks2) {
                bf16x8 vf = *(const bf16x8*)&vs[mt * 16 + ln][ks2 * 32 + quad * 8];
                oacc[mt][0] = MFMA16(vf, pb[ks2][0], oacc[mt][0]);
                oacc[mt][1] = MFMA16(vf, pb[ks2][1], oacc[mt][1]);
            }
        __syncthreads();
    }

    // l: sum over keys lives per-lane; reduce across the 4 quad-groups (xor 16, 32)
    for (int nt = 0; nt < 2; ++nt) {
        float s = rs[nt];
        s += __shfl_xor(s, 16);
        s += __shfl_xor(s, 32);
        int row = m0 + w * 32 + nt * 16 + ln;
        if (quad == 0)
            Ln[((size_t)split * 4096 + row) * 16 + h] = s;
        // O^T C-frag: 4 consecutive d per lane -> b64 f16 stores (4 quads cover 32B/row-tile)
        for (int mt = 0; mt < 8; ++mt) {
            f16x4 o;
            for (int r = 0; r < 4; ++r) o[r] = (_Float16)oacc[mt][nt][r];
            *(f16x4*)&On[((size_t)split * 4096 + row) * 2048 + h * 128 + mt * 16 + quad * 4] = o;
        }
    }
}

// ---------------- combine: ctx = (On0 + On1) / (l0 + l1) ----------------
__global__ __launch_bounds__(256) void flash_combine(const _Float16* __restrict__ On,
                                                     const float* __restrict__ Ln,
                                                     __bf16* __restrict__ ctx) {
    int s = blockIdx.x;
    int c0 = threadIdx.x * 8;
    int h = c0 >> 7;
    f16x8 a = *(const f16x8*)&On[(size_t)s * 2048 + c0];
    f16x8 b = *(const f16x8*)&On[((size_t)4096 + s) * 2048 + c0];
    float l = Ln[(size_t)s * 16 + h] + Ln[((size_t)4096 + s) * 16 + h];
    float inv = 1.0f / l;
    bf16x8 o;
    for (int k = 0; k < 8; ++k) o[k] = (__bf16)(((float)a[k] + (float)b[k]) * inv);
    *(bf16x8*)&ctx[(size_t)s * 2048 + c0] = o;
}

// ---------------- launch ----------------
extern "C" void kernel_launch(void* const* d_in, const int* in_sizes, int n_in,
                              void* d_out, int out_size, void* d_ws, size_t ws_size,
                              hipStream_t stream) {
    const float* hs  = (const float*)d_in[0];
    const int*   pos = (const int*)d_in[1];
    const float* wq  = (const float*)d_in[2];
    const float* wk  = (const float*)d_in[3];
    const float* wv  = (const float*)d_in[4];
    const float* wo  = (const float*)d_in[5];
    const float* qw  = (const float*)d_in[6];
    const float* kw  = (const float*)d_in[7];

    char* ws = (char*)d_ws;
    const size_t MB = 1024 * 1024;
    __bf16*   xb     = (__bf16*)(ws + 0);
    __bf16*   wqkvtb = (__bf16*)(ws + 16 * MB);
    __bf16*   qhb    = (__bf16*)(ws + 0);
    __bf16*   khb    = (__bf16*)(ws + 16 * MB);
    __bf16*   vtb    = (__bf16*)(ws + 32 * MB);
    __bf16*   qkvb   = (__bf16*)(ws + 48 * MB);
    _Float16* Onb    = (_Float16*)(ws + 48 * MB);
    float*    Lnb    = (float*)(ws + 80 * MB);
    __bf16*   ctxb   = (__bf16*)(ws + 0);
    __bf16*   wotb   = (__bf16*)(ws + 96 * MB);

    dim3 tb(32, 8);
    convert_f32_bf16<<<8192, 256, 0, stream>>>(hs, xb);
    transpose_conv<<<dim3(64, 64), tb, 0, stream>>>(wq, wqkvtb);
    transpose_conv<<<dim3(64, 64), tb, 0, stream>>>(wk, wqkvtb + (size_t)2048 * 2048);
    transpose_conv<<<dim3(64, 64), tb, 0, stream>>>(wv, wqkvtb + (size_t)2 * 2048 * 2048);
    transpose_conv<<<dim3(64, 64), tb, 0, stream>>>(wo, wotb);

    gemm_bt<false><<<dim3(32, 48), 256, 0, stream>>>(xb, 2048, wqkvtb, 2048, qkvb, 6144, 2048);

    rmsrope<<<32768, 256, 0, stream>>>(qkvb, qw, kw, pos, qhb, khb);
    v_transpose<<<dim3(128, 4, 16), tb, 0, stream>>>(qkvb, vtb);

    flash_attn<<<dim3(32, 16, 2), 256, 0, stream>>>(qhb, khb, vtb, Onb, Lnb);
    flash_combine<<<4096, 256, 0, stream>>>(Onb, Lnb, ctxb);

    gemm_bt<true><<<dim3(32, 16), 256, 0, stream>>>(ctxb, 2048, wotb, 2048, d_out, 2048, 2048);
}